// Round 1
// baseline (455.528 us; speedup 1.0000x reference)
//
#include <hip/hip_runtime.h>

#define SINKHORN_ITERS 20
#define N_STREAMS 4
#define DDIM 1024
#define BT_PER_BLOCK 8   // 2048 blocks = 8 blocks/CU; full CU wave capacity

// Native clang vector type — lowers to global_load/store_dwordx4.
typedef float f32x4 __attribute__((ext_vector_type(4)));

// Fused kernel: every wave redundantly computes sinkhorn(H_raw) (4x4) via
// lane-parallel xor-shuffles (bit-identical across waves), then streams
// out[bt,n,d] = sum_m H[n][m] * x[bt,m,d].
//
// v2 changes vs the 435.6 µs baseline:
//  - chunk-0 loads issued BEFORE sinkhorn (HBM latency hides the ~1.4k-cycle
//    shuffle loop instead of serializing in front of it)
//  - 2-deep software pipeline on the bt loop (next chunk's 4 loads are in
//    flight while the current chunk computes+stores)
//  - PLAIN loads for x (m13's 6.29 TB/s copy ceiling was measured with plain
//    loads; nt on the read path buys nothing for cold use-once data and risks
//    read-side TCC efficiency). Stores stay nontemporal: out is never re-read
//    and wave-contiguous 1 KiB writes are full-line.
//  - H broadcast via v_readlane into SGPRs (frees 16 VGPRs; FMAs take H as a
//    scalar operand, keeping the pipelined body at full occupancy)
__global__ __launch_bounds__(256) void fused_mix_k(const float* __restrict__ x,
                                                   const float* __restrict__ H_raw,
                                                   float* __restrict__ out,
                                                   int n_bt) {
    const int tid = threadIdx.x;
    const int lane = tid & 63;

    const int C = DDIM / 4;          // 256 float4 per (bt, stream) chunk
    const int dv = tid;              // 0..255: float4 index within a chunk
    const int bt0 = blockIdx.x * BT_PER_BLOCK;

    // ---- issue chunk 0's loads first: they cover sinkhorn's latency ----
    const f32x4* xb = (const f32x4*)x + (size_t)bt0 * (N_STREAMS * C) + dv;
    f32x4 x0 = xb[0 * C];
    f32x4 x1 = xb[1 * C];
    f32x4 x2 = xb[2 * C];
    f32x4 x3 = xb[3 * C];

    // ---- per-wave sinkhorn (runs while the 4 loads above are in flight) ----
    // Lane k holds A[i][j], i=(k>>2)&3, j=k&3; lanes 16..63 carry replicas so
    // the 16-lane butterflies stay closed.
    float A = fabsf(H_raw[lane & 15]) + 1e-8f;
#pragma unroll 1
    for (int it = 0; it < SINKHORN_ITERS; ++it) {
        float r1 = A + __shfl_xor(A, 1);
        float rs = r1 + __shfl_xor(r1, 2);   // row sum (axis=1)
        A = A / rs;
        float c1 = A + __shfl_xor(A, 4);
        float cs = c1 + __shfl_xor(c1, 8);   // col sum (axis=0)
        A = A / cs;
    }
    // Broadcast into SGPRs: h[k] is wave-uniform, v_readlane ignores exec and
    // lands in the scalar file — no VGPR cost, FMA reads it as the 1 allowed
    // scalar operand.
    float h[16];
#pragma unroll
    for (int k = 0; k < 16; ++k)
        h[k] = __uint_as_float(__builtin_amdgcn_readlane(__float_as_uint(A), k));

    // ---- streaming mix, 2-deep pipelined ----
#pragma unroll 1
    for (int g = 0; g < BT_PER_BLOCK; ++g) {
        const int bt = bt0 + g;
        if (bt >= n_bt) break;

        // prefetch next chunk before touching (waiting on) the current one
        f32x4 y0, y1, y2, y3;
        const bool pf = (g + 1 < BT_PER_BLOCK) && (bt + 1 < n_bt);
        if (pf) {
            const f32x4* xq = (const f32x4*)x + (size_t)(bt + 1) * (N_STREAMS * C) + dv;
            y0 = xq[0 * C];
            y1 = xq[1 * C];
            y2 = xq[2 * C];
            y3 = xq[3 * C];
        }

        f32x4* op = (f32x4*)out + (size_t)bt * (N_STREAMS * C) + dv;
#pragma unroll
        for (int n = 0; n < 4; ++n) {
            f32x4 o = h[n * 4 + 0] * x0 + h[n * 4 + 1] * x1 +
                      h[n * 4 + 2] * x2 + h[n * 4 + 3] * x3;
            __builtin_nontemporal_store(o, op + n * C);
        }

        if (pf) { x0 = y0; x1 = y1; x2 = y2; x3 = y3; }
    }
}

extern "C" void kernel_launch(void* const* d_in, const int* in_sizes, int n_in,
                              void* d_out, int out_size, void* d_ws, size_t ws_size,
                              hipStream_t stream) {
    const float* x = (const float*)d_in[0];
    const float* H_raw = (const float*)d_in[1];
    float* out = (float*)d_out;

    int n_bt = in_sizes[0] / (N_STREAMS * DDIM);            // = B*T = 16384
    int blocks = (n_bt + BT_PER_BLOCK - 1) / BT_PER_BLOCK;  // = 2048
    fused_mix_k<<<blocks, 256, 0, stream>>>(x, H_raw, out, n_bt);
}

// Round 3
// 450.599 us; speedup vs baseline: 1.0109x; 1.0109x over previous
//
#include <hip/hip_runtime.h>

#define SINKHORN_ITERS 20
#define N_STREAMS 4
#define DDIM 1024
#define BT_PER_BLOCK 8   // 2048 blocks = 8 blocks/CU; full CU wave capacity

// Native clang vector type — lowers to global_load/store_dwordx4.
typedef float f32x4 __attribute__((ext_vector_type(4)));

// Fused kernel: every wave redundantly computes sinkhorn(H_raw) (4x4) via
// lane-parallel xor-shuffles (bit-identical across waves), then streams
// out[bt,n,d] = sum_m H[n][m] * x[bt,m,d].
//
// v3 theory (from v2 counters: VGPR=24, VALUBusy 7.8%, 2.4 TB/s — stall-bound):
// vmcnt decrements in ISSUE order, so a wait for freshly-issued loads also
// drains all older outstanding NT stores. v1/v2 issued loads AFTER the
// previous chunk's stores, so every iteration serialized on store-completion
// to HBM. v3 rotates the loop: the NEXT chunk's 4 loads are issued BEFORE the
// current chunk's stores, branch-free, two live register buffers. The wait
// before the FMAs is then a counted vmcnt covering only loads; each store
// gets a full iteration of slack to retire off the counter.
//
// Cache policy (from v2 counters: FETCH=134 MB = half of x served by L3):
// plain loads (keep L3 hits), nontemporal stores (out is never re-read;
// allocating 268 MB of stores would evict the warm half of x).
__global__ __launch_bounds__(256) void fused_mix_k(const float* __restrict__ x,
                                                   const float* __restrict__ H_raw,
                                                   float* __restrict__ out,
                                                   int n_bt) {
    const int tid = threadIdx.x;
    const int lane = tid & 63;

    const int C = DDIM / 4;             // 256 float4 per (bt, stream) chunk
    const int STRIDE = N_STREAMS * C;   // 1024 float4 per bt
    const int bt0 = blockIdx.x * BT_PER_BLOCK;

    const f32x4* xp = (const f32x4*)x + (size_t)bt0 * STRIDE + tid;
    f32x4* op = (f32x4*)out + (size_t)bt0 * STRIDE + tid;

    // ---- chunk 0 loads first: they fly while sinkhorn runs ----
    // (grid is sized so bt0 < n_bt always; chunk 0 is always valid)
    f32x4 a0 = xp[0 * C];
    f32x4 a1 = xp[1 * C];
    f32x4 a2 = xp[2 * C];
    f32x4 a3 = xp[3 * C];

    // ---- per-wave sinkhorn (hidden under the loads above) ----
    // Lane k holds A[i][j], i=(k>>2)&3, j=k&3; lanes 16..63 carry replicas so
    // the 16-lane butterflies stay closed.
    float A = fabsf(H_raw[lane & 15]) + 1e-8f;
#pragma unroll 1
    for (int it = 0; it < SINKHORN_ITERS; ++it) {
        float r1 = A + __shfl_xor(A, 1);
        float rs = r1 + __shfl_xor(r1, 2);   // row sum (axis=1)
        A = A / rs;
        float c1 = A + __shfl_xor(A, 4);
        float cs = c1 + __shfl_xor(c1, 8);   // col sum (axis=0)
        A = A / cs;
    }
    // Wave-uniform broadcast into SGPRs (readlane ignores exec, no VGPR cost;
    // v_fma takes one scalar operand directly).
    float h[16];
#pragma unroll
    for (int k = 0; k < 16; ++k)
        h[k] = __uint_as_float(__builtin_amdgcn_readlane(__float_as_uint(A), k));

    if (bt0 + BT_PER_BLOCK <= n_bt) {
        // ---- fast path: branch-free rotated 2-buffer pipeline ----
#pragma unroll 1
        for (int g = 0; g < BT_PER_BLOCK - 1; ++g) {
            // next chunk's loads issue BEFORE this chunk's stores
            const f32x4* xn = xp + (size_t)(g + 1) * STRIDE;
            f32x4 b0 = xn[0 * C];
            f32x4 b1 = xn[1 * C];
            f32x4 b2 = xn[2 * C];
            f32x4 b3 = xn[3 * C];

            f32x4* o = op + (size_t)g * STRIDE;
#pragma unroll
            for (int n = 0; n < 4; ++n) {
                f32x4 v = h[n * 4 + 0] * a0 + h[n * 4 + 1] * a1 +
                          h[n * 4 + 2] * a2 + h[n * 4 + 3] * a3;
                __builtin_nontemporal_store(v, o + n * C);
            }
            a0 = b0; a1 = b1; a2 = b2; a3 = b3;
        }
        // epilogue: last chunk
        f32x4* o = op + (size_t)(BT_PER_BLOCK - 1) * STRIDE;
#pragma unroll
        for (int n = 0; n < 4; ++n) {
            f32x4 v = h[n * 4 + 0] * a0 + h[n * 4 + 1] * a1 +
                      h[n * 4 + 2] * a2 + h[n * 4 + 3] * a3;
            __builtin_nontemporal_store(v, o + n * C);
        }
    } else {
        // ---- tail path (never taken when n_bt % BT_PER_BLOCK == 0) ----
#pragma unroll 1
        for (int g = 0; g < BT_PER_BLOCK; ++g) {
            int bt = bt0 + g;
            if (bt >= n_bt) break;
            if (g > 0) {
                const f32x4* xn = xp + (size_t)g * STRIDE;
                a0 = xn[0 * C];
                a1 = xn[1 * C];
                a2 = xn[2 * C];
                a3 = xn[3 * C];
            }
            f32x4* o = op + (size_t)g * STRIDE;
#pragma unroll
            for (int n = 0; n < 4; ++n) {
                f32x4 v = h[n * 4 + 0] * a0 + h[n * 4 + 1] * a1 +
                          h[n * 4 + 2] * a2 + h[n * 4 + 3] * a3;
                __builtin_nontemporal_store(v, o + n * C);
            }
        }
    }
}

extern "C" void kernel_launch(void* const* d_in, const int* in_sizes, int n_in,
                              void* d_out, int out_size, void* d_ws, size_t ws_size,
                              hipStream_t stream) {
    const float* x = (const float*)d_in[0];
    const float* H_raw = (const float*)d_in[1];
    float* out = (float*)d_out;

    int n_bt = in_sizes[0] / (N_STREAMS * DDIM);            // = B*T = 16384
    int blocks = (n_bt + BT_PER_BLOCK - 1) / BT_PER_BLOCK;  // = 2048
    fused_mix_k<<<blocks, 256, 0, stream>>>(x, H_raw, out, n_bt);
}

// Round 5
// 437.531 us; speedup vs baseline: 1.0411x; 1.0299x over previous
//
#include <hip/hip_runtime.h>

#define SINKHORN_ITERS 20
#define N_STREAMS 4
#define DDIM 1024
#define BT_PER_BLOCK 8   // 2048 blocks = 8 blocks/CU; full CU wave capacity

// Native clang vector type — lowers to global_load/store_dwordx4.
typedef float f32x4 __attribute__((ext_vector_type(4)));

// Fused kernel: every wave redundantly computes sinkhorn(H_raw) (4x4) via
// lane-parallel xor-shuffles (bit-identical across waves), then streams
// out[bt,n,d] = sum_m H[n][m] * x[bt,m,d].
//
// v4 theory (post-mortem of v3: rotated pipeline survived — VGPR 36 — but
// gained only 3 µs; VALUBusy 8.2% matches hand-counted VALU cycles, so waves
// idle ~92% on a SHARED throughput cap, not on waitcnt ordering): the only
// store path never observed above 1.65 TB/s in this session is the
// nontemporal one, while the harness's fill kernels sustain 6.3-6.5 TB/s on
// the plain L2-writeback store path. v4 switches to PLAIN stores as the
// single variable. Cost ceiling: losing L3-warm x half ≈ 21 µs; upside if
// NT-store path is the cap: ~60-70 µs.
//
// Loads stay plain (v2 counters showed FETCH = 134 MB = half of x served
// from L3 — keep those hits).
__global__ __launch_bounds__(256) void fused_mix_k(const float* __restrict__ x,
                                                   const float* __restrict__ H_raw,
                                                   float* __restrict__ out,
                                                   int n_bt) {
    const int tid = threadIdx.x;
    const int lane = tid & 63;

    const int C = DDIM / 4;             // 256 float4 per (bt, stream) chunk
    const int STRIDE = N_STREAMS * C;   // 1024 float4 per bt
    const int bt0 = blockIdx.x * BT_PER_BLOCK;

    const f32x4* xp = (const f32x4*)x + (size_t)bt0 * STRIDE + tid;
    f32x4* op = (f32x4*)out + (size_t)bt0 * STRIDE + tid;

    // ---- chunk 0 loads first: they fly while sinkhorn runs ----
    f32x4 a0 = xp[0 * C];
    f32x4 a1 = xp[1 * C];
    f32x4 a2 = xp[2 * C];
    f32x4 a3 = xp[3 * C];

    // ---- per-wave sinkhorn (hidden under the loads above) ----
    // Lane k holds A[i][j], i=(k>>2)&3, j=k&3; lanes 16..63 carry replicas so
    // the 16-lane butterflies stay closed.
    float A = fabsf(H_raw[lane & 15]) + 1e-8f;
#pragma unroll 1
    for (int it = 0; it < SINKHORN_ITERS; ++it) {
        float r1 = A + __shfl_xor(A, 1);
        float rs = r1 + __shfl_xor(r1, 2);   // row sum (axis=1)
        A = A / rs;
        float c1 = A + __shfl_xor(A, 4);
        float cs = c1 + __shfl_xor(c1, 8);   // col sum (axis=0)
        A = A / cs;
    }
    // Wave-uniform broadcast into SGPRs (readlane ignores exec, no VGPR cost;
    // v_fma takes one scalar operand directly).
    float h[16];
#pragma unroll
    for (int k = 0; k < 16; ++k)
        h[k] = __uint_as_float(__builtin_amdgcn_readlane(__float_as_uint(A), k));

    if (bt0 + BT_PER_BLOCK <= n_bt) {
        // ---- fast path: branch-free rotated 2-buffer pipeline ----
#pragma unroll 1
        for (int g = 0; g < BT_PER_BLOCK - 1; ++g) {
            // next chunk's loads issue BEFORE this chunk's stores
            const f32x4* xn = xp + (size_t)(g + 1) * STRIDE;
            f32x4 b0 = xn[0 * C];
            f32x4 b1 = xn[1 * C];
            f32x4 b2 = xn[2 * C];
            f32x4 b3 = xn[3 * C];

            f32x4* o = op + (size_t)g * STRIDE;
#pragma unroll
            for (int n = 0; n < 4; ++n) {
                f32x4 v = h[n * 4 + 0] * a0 + h[n * 4 + 1] * a1 +
                          h[n * 4 + 2] * a2 + h[n * 4 + 3] * a3;
                o[n * C] = v;
            }
            a0 = b0; a1 = b1; a2 = b2; a3 = b3;
        }
        // epilogue: last chunk
        f32x4* o = op + (size_t)(BT_PER_BLOCK - 1) * STRIDE;
#pragma unroll
        for (int n = 0; n < 4; ++n) {
            f32x4 v = h[n * 4 + 0] * a0 + h[n * 4 + 1] * a1 +
                      h[n * 4 + 2] * a2 + h[n * 4 + 3] * a3;
            o[n * C] = v;
        }
    } else {
        // ---- tail path (never taken when n_bt % BT_PER_BLOCK == 0) ----
#pragma unroll 1
        for (int g = 0; g < BT_PER_BLOCK; ++g) {
            int bt = bt0 + g;
            if (bt >= n_bt) break;
            if (g > 0) {
                const f32x4* xn = xp + (size_t)g * STRIDE;
                a0 = xn[0 * C];
                a1 = xn[1 * C];
                a2 = xn[2 * C];
                a3 = xn[3 * C];
            }
            f32x4* o = op + (size_t)g * STRIDE;
#pragma unroll
            for (int n = 0; n < 4; ++n) {
                f32x4 v = h[n * 4 + 0] * a0 + h[n * 4 + 1] * a1 +
                          h[n * 4 + 2] * a2 + h[n * 4 + 3] * a3;
                o[n * C] = v;
            }
        }
    }
}

extern "C" void kernel_launch(void* const* d_in, const int* in_sizes, int n_in,
                              void* d_out, int out_size, void* d_ws, size_t ws_size,
                              hipStream_t stream) {
    const float* x = (const float*)d_in[0];
    const float* H_raw = (const float*)d_in[1];
    float* out = (float*)d_out;

    int n_bt = in_sizes[0] / (N_STREAMS * DDIM);            // = B*T = 16384
    int blocks = (n_bt + BT_PER_BLOCK - 1) / BT_PER_BLOCK;  // = 2048
    fused_mix_k<<<blocks, 256, 0, stream>>>(x, H_raw, out, n_bt);
}

// Round 6
// 428.503 us; speedup vs baseline: 1.0631x; 1.0211x over previous
//
#include <hip/hip_runtime.h>

#define SINKHORN_ITERS 20
#define N_STREAMS 4
#define DDIM 1024
#define BT_PER_BLOCK 2   // 8192 blocks = 32 queued/CU: finished blocks are
                         // replaced, keeping wave slots full through the tail
                         // (v4's 2048-block grid = exactly 8/CU, no reserve;
                         // OccupancyPercent sagged to ~53%)

// Native clang vector type — lowers to global_load/store_dwordx4.
typedef float f32x4 __attribute__((ext_vector_type(4)));

// Fused kernel: every wave redundantly computes sinkhorn(H_raw) (4x4) via
// lane-parallel xor-shuffles (bit-identical across waves), then streams
// out[bt,n,d] = sum_m H[n][m] * x[bt,m,d].
//
// Cache-policy matrix (measured, kernel-only time):
//   NT load / NT store      ~105 us   (v0)
//   plain load / NT store   ~165 us   (v2/v3 — pathological TCC interaction)
//   plain load / plain store~107 us   (v4)
// -> keep plain/plain. Stores allocate normally; loads keep L3 hits on the
//    restore-warm half of x.
//
// v5 single variable: BT_PER_BLOCK 8 -> 2. Both fast variants run at only
// ~5.1 TB/s effective vs the 6.3 TB/s copy ceiling, VALUBusy ~8%, MLP ample —
// the remaining signal is the exact-fit grid (no block replacement -> tail
// drain). 4x more blocks smooths it; extra per-block sinkhorn is VALU work
// hidden under prologue loads (92% VALU headroom).
__global__ __launch_bounds__(256) void fused_mix_k(const float* __restrict__ x,
                                                   const float* __restrict__ H_raw,
                                                   float* __restrict__ out,
                                                   int n_bt) {
    const int tid = threadIdx.x;
    const int lane = tid & 63;

    const int C = DDIM / 4;             // 256 float4 per (bt, stream) chunk
    const int STRIDE = N_STREAMS * C;   // 1024 float4 per bt
    const int bt0 = blockIdx.x * BT_PER_BLOCK;

    const f32x4* xp = (const f32x4*)x + (size_t)bt0 * STRIDE + tid;
    f32x4* op = (f32x4*)out + (size_t)bt0 * STRIDE + tid;

    // ---- chunk 0 loads first: they fly while sinkhorn runs ----
    f32x4 a0 = xp[0 * C];
    f32x4 a1 = xp[1 * C];
    f32x4 a2 = xp[2 * C];
    f32x4 a3 = xp[3 * C];

    // ---- per-wave sinkhorn (hidden under the loads above) ----
    // Lane k holds A[i][j], i=(k>>2)&3, j=k&3; lanes 16..63 carry replicas so
    // the 16-lane butterflies stay closed.
    float A = fabsf(H_raw[lane & 15]) + 1e-8f;
#pragma unroll 1
    for (int it = 0; it < SINKHORN_ITERS; ++it) {
        float r1 = A + __shfl_xor(A, 1);
        float rs = r1 + __shfl_xor(r1, 2);   // row sum (axis=1)
        A = A / rs;
        float c1 = A + __shfl_xor(A, 4);
        float cs = c1 + __shfl_xor(c1, 8);   // col sum (axis=0)
        A = A / cs;
    }
    // Wave-uniform broadcast into SGPRs (readlane ignores exec, no VGPR cost;
    // v_fma takes one scalar operand directly).
    float h[16];
#pragma unroll
    for (int k = 0; k < 16; ++k)
        h[k] = __uint_as_float(__builtin_amdgcn_readlane(__float_as_uint(A), k));

    if (bt0 + BT_PER_BLOCK <= n_bt) {
        // ---- fast path: branch-free rotated 2-buffer pipeline ----
#pragma unroll 1
        for (int g = 0; g < BT_PER_BLOCK - 1; ++g) {
            // next chunk's loads issue BEFORE this chunk's stores
            const f32x4* xn = xp + (size_t)(g + 1) * STRIDE;
            f32x4 b0 = xn[0 * C];
            f32x4 b1 = xn[1 * C];
            f32x4 b2 = xn[2 * C];
            f32x4 b3 = xn[3 * C];

            f32x4* o = op + (size_t)g * STRIDE;
#pragma unroll
            for (int n = 0; n < 4; ++n) {
                f32x4 v = h[n * 4 + 0] * a0 + h[n * 4 + 1] * a1 +
                          h[n * 4 + 2] * a2 + h[n * 4 + 3] * a3;
                o[n * C] = v;
            }
            a0 = b0; a1 = b1; a2 = b2; a3 = b3;
        }
        // epilogue: last chunk
        f32x4* o = op + (size_t)(BT_PER_BLOCK - 1) * STRIDE;
#pragma unroll
        for (int n = 0; n < 4; ++n) {
            f32x4 v = h[n * 4 + 0] * a0 + h[n * 4 + 1] * a1 +
                      h[n * 4 + 2] * a2 + h[n * 4 + 3] * a3;
            o[n * C] = v;
        }
    } else {
        // ---- tail path (never taken when n_bt % BT_PER_BLOCK == 0) ----
#pragma unroll 1
        for (int g = 0; g < BT_PER_BLOCK; ++g) {
            int bt = bt0 + g;
            if (bt >= n_bt) break;
            if (g > 0) {
                const f32x4* xn = xp + (size_t)g * STRIDE;
                a0 = xn[0 * C];
                a1 = xn[1 * C];
                a2 = xn[2 * C];
                a3 = xn[3 * C];
            }
            f32x4* o = op + (size_t)g * STRIDE;
#pragma unroll
            for (int n = 0; n < 4; ++n) {
                f32x4 v = h[n * 4 + 0] * a0 + h[n * 4 + 1] * a1 +
                          h[n * 4 + 2] * a2 + h[n * 4 + 3] * a3;
                o[n * C] = v;
            }
        }
    }
}

extern "C" void kernel_launch(void* const* d_in, const int* in_sizes, int n_in,
                              void* d_out, int out_size, void* d_ws, size_t ws_size,
                              hipStream_t stream) {
    const float* x = (const float*)d_in[0];
    const float* H_raw = (const float*)d_in[1];
    float* out = (float*)d_out;

    int n_bt = in_sizes[0] / (N_STREAMS * DDIM);            // = B*T = 16384
    int blocks = (n_bt + BT_PER_BLOCK - 1) / BT_PER_BLOCK;  // = 8192
    fused_mix_k<<<blocks, 256, 0, stream>>>(x, H_raw, out, n_bt);
}